// Round 8
// baseline (199.577 us; speedup 1.0000x reference)
//
#include <hip/hip_runtime.h>

// Problem constants: B=64, I=512, H=1024, D=I+H=1536
constexpr int Bn = 64;
constexpr int In = 512;
constexpr int Hn = 1024;
constexpr int Dn = 1536;
constexpr float ALPHA = 0.001f;

typedef float nfloat4 __attribute__((ext_vector_type(4)));

// R8: LAYOUT-ORDER traversal. Block = (b, chunk of 64 consecutive k).
//   - wih/out_wih rows for one block = 384 KB CONTIGUOUS (previous rounds:
//     6 KB chunks at 6 MB stride -> DRAM page/bank thrash; flat 161-168 us
//     across occupancy 22-64% and prefetch depth 0-2 ruled out latency).
//   - 4 waves interleave on k (wave wv owns k = k0+wv+4i): at any instant the
//     block reads/writes a dense sliding 24 KB window.
//   - x[b,:] is block-invariant -> 24 VGPR, loaded ONCE (was a per-row L2 read).
//   - W rows stream from L2: blocks sharing a k-chunk are bid = b*16+kc,
//     stride 16 -> same XCD under round-robin -> 1.5 MB W chunk is L2-resident
//     with 64x reuse. No LDS, no barriers.
//   - update folds ALPHA: o = fma(a*y, t1, fma(a, t2, w)), t1=fma(x,A,C),
//     t2=fma(x,B,D) -> 4 FMA/elem.
__global__ __launch_bounds__(256) void prnn_fused_kernel(
    const float* __restrict__ inputs,   // B x I
    const float* __restrict__ hidden,   // B x H
    const float* __restrict__ wih,      // B x H x D
    const float* __restrict__ Wa,       // H x D
    const float* __restrict__ Wb,       // H x D
    const float* __restrict__ Wc,       // H x D
    const float* __restrict__ Wd,       // H x D
    const float* __restrict__ bih,      // H
    float* __restrict__ out_hidden,     // B x H
    float* __restrict__ out_wih)        // B x H x D
{
    const int bid  = blockIdx.x;
    const int k0   = (bid & 15) << 6;    // k-chunk base (16 chunks of 64)
    const int b    = bid >> 4;
    const int wv   = threadIdx.x >> 6;
    const int lane = threadIdx.x & 63;
    const int base = lane * 4;

    // x[b,:] resident in registers for the whole block (6 KB / wave).
    nfloat4 x[6];
    {
        const float* __restrict__ xin = inputs + b * In;
        const float* __restrict__ xh  = hidden + b * Hn;
        #pragma unroll
        for (int c = 0; c < 6; ++c) {
            const int idx = c * 256 + base;
            x[c] = (c < 2) ? *(const nfloat4*)(xin + idx)
                           : *(const nfloat4*)(xh + (idx - In));
        }
    }

    nfloat4 wb2[2][6];                  // wih row double-buffer (48 VGPR)

    auto wrow_ptr = [&](int i) {
        const int k = k0 + wv + (i << 2);
        return wih + ((size_t)b * Hn + k) * Dn;
    };

    {   // prologue: row 0 in flight
        const float* __restrict__ p = wrow_ptr(0);
        #pragma unroll
        for (int c = 0; c < 6; ++c)
            wb2[0][c] = *(const nfloat4*)(p + c * 256 + base);
    }

    #pragma unroll
    for (int i = 0; i < 16; ++i) {      // fully unrolled: static buffer indices
        const int k = k0 + wv + (i << 2);

        if (i + 1 < 16) {               // prefetch next wih row (HBM stream)
            const float* __restrict__ p = wrow_ptr(i + 1);
            #pragma unroll
            for (int c = 0; c < 6; ++c)
                wb2[(i + 1) & 1][c] = *(const nfloat4*)(p + c * 256 + base);
        }
        nfloat4 (&w)[6] = wb2[i & 1];

        float acc = 0.0f;
        #pragma unroll
        for (int c = 0; c < 6; ++c) {
            const nfloat4 p = w[c] * x[c];
            acc += (p.x + p.y) + (p.z + p.w);
        }
        #pragma unroll
        for (int off = 32; off > 0; off >>= 1)
            acc += __shfl_xor(acc, off, 64);

        const float y  = tanhf(acc + bih[k]);
        const float ay = ALPHA * y;
        if (lane == 0) out_hidden[b * Hn + k] = y;

        const float* __restrict__ pa = Wa + (size_t)k * Dn;
        const float* __restrict__ pb = Wb + (size_t)k * Dn;
        const float* __restrict__ pc = Wc + (size_t)k * Dn;
        const float* __restrict__ pd = Wd + (size_t)k * Dn;
        float* __restrict__ orow = out_wih + ((size_t)b * Hn + k) * Dn;

        #pragma unroll
        for (int c = 0; c < 6; ++c) {
            const int idx = c * 256 + base;
            const nfloat4 a4 = *(const nfloat4*)(pa + idx);
            const nfloat4 b4 = *(const nfloat4*)(pb + idx);
            const nfloat4 c4 = *(const nfloat4*)(pc + idx);
            const nfloat4 d4 = *(const nfloat4*)(pd + idx);
            const nfloat4 t1 = x[c] * a4 + c4;
            const nfloat4 t2 = x[c] * b4 + d4;
            nfloat4 o = w[c] + ALPHA * t2;
            o = o + ay * t1;
            __builtin_nontemporal_store(o, (nfloat4*)(orow + idx));
        }
    }
}

extern "C" void kernel_launch(void* const* d_in, const int* in_sizes, int n_in,
                              void* d_out, int out_size, void* d_ws, size_t ws_size,
                              hipStream_t stream) {
    const float* inputs = (const float*)d_in[0];
    const float* hidden = (const float*)d_in[1];
    const float* wih    = (const float*)d_in[2];
    const float* Wa     = (const float*)d_in[3];
    const float* Wb     = (const float*)d_in[4];
    const float* Wc     = (const float*)d_in[5];
    const float* Wd     = (const float*)d_in[6];
    const float* bih    = (const float*)d_in[7];
    // d_in[8] = W_dop, d_in[9] = b_dop feed only _dopamine (not returned) -> skipped.

    float* out_hidden = (float*)d_out;                    // B*H floats
    float* out_wih    = (float*)d_out + (size_t)Bn * Hn;  // B*H*D floats

    // 64 b x 16 k-chunks = 1024 blocks x 256 threads.
    prnn_fused_kernel<<<dim3(Bn * 16), dim3(256), 0, stream>>>(
        inputs, hidden, wih, Wa, Wb, Wc, Wd, bih, out_hidden, out_wih);
}

// Round 9
// 159.068 us; speedup vs baseline: 1.2547x; 1.2547x over previous
//
#include <hip/hip_runtime.h>

// Problem constants: B=64, I=512, H=1024, D=I+H=1536
constexpr int Bn = 64;
constexpr int In = 512;
constexpr int Hn = 1024;
constexpr int Dn = 1536;
constexpr float ALPHA = 0.001f;
constexpr int RPW = 16;                // rows per wave (all 64 b per block)

// Native 4-float vector for __builtin_nontemporal_store.
typedef float nfloat4 __attribute__((ext_vector_type(4)));

// R9 = R4 champion (161.0 us) + ONE isolated change: x prefetched 1 row deep.
// Mechanism: in R4, x(i) is issued and consumed within the same iteration --
// ~250 cyc of L2 latency exposed at every row top, and the implicit
// s_waitcnt for x(i) (in-order vmcnt) force-drains the previous row's NT
// stores. With x(i+1) issued one row early, the row-top wait covers only
// data that has had a full row of compute+stores to land, and store
// retirement gets a row of slack. Cost: +24 VGPR (keeps ~3-4 waves/SIMD).
__global__ __launch_bounds__(256) void prnn_fused_kernel(
    const float* __restrict__ inputs,   // B x I
    const float* __restrict__ hidden,   // B x H
    const float* __restrict__ wih,      // B x H x D
    const float* __restrict__ Wa,       // H x D
    const float* __restrict__ Wb,       // H x D
    const float* __restrict__ Wc,       // H x D
    const float* __restrict__ Wd,       // H x D
    const float* __restrict__ bih,      // H
    float* __restrict__ out_hidden,     // B x H
    float* __restrict__ out_wih)        // B x H x D
{
    __shared__ float4 sW[4 * (Dn / 4)];   // 24 KB

    const int k   = blockIdx.x;
    const int tid = threadIdx.x;

    // Cooperative LDS stage of Wa..Wd row k (384 float4 per tensor).
    {
        const float4* wa4 = (const float4*)(Wa + (size_t)k * Dn);
        const float4* wb4 = (const float4*)(Wb + (size_t)k * Dn);
        const float4* wc4 = (const float4*)(Wc + (size_t)k * Dn);
        const float4* wd4 = (const float4*)(Wd + (size_t)k * Dn);
        #pragma unroll
        for (int e = 0; e < 2; ++e) {
            const int i = tid + e * 256;
            if (i < 384) {
                sW[i]        = wa4[i];
                sW[384 + i]  = wb4[i];
                sW[768 + i]  = wc4[i];
                sW[1152 + i] = wd4[i];
            }
        }
    }
    __syncthreads();

    const int wave = tid >> 6;
    const int lane = tid & 63;
    const int b0   = wave * RPW;
    const float bk = bih[k];
    const int base = lane * 4;

    float4 wbuf[3][6];   // wih: 2-row-deep prefetch (3 rotating buffers)
    float4 xbuf[2][6];   // x:   1-row-deep prefetch (NEW vs R4)

    auto load_w = [&](int r, float4 (&w)[6]) {
        const float* __restrict__ wrow = wih + ((size_t)(b0 + r) * Hn + k) * Dn;
        #pragma unroll
        for (int c = 0; c < 6; ++c)
            w[c] = *(const float4*)(wrow + c * 256 + base);
    };
    auto load_x = [&](int r, float4 (&x)[6]) {
        const int b = b0 + r;
        const float* __restrict__ xin  = inputs + b * In;
        const float* __restrict__ xhid = hidden + b * Hn;
        #pragma unroll
        for (int c = 0; c < 6; ++c) {
            const int idx = c * 256 + base;
            x[c] = (c < 2) ? *(const float4*)(xin + idx)
                           : *(const float4*)(xhid + (idx - In));
        }
    };

    // Prologue: 2 rows of wih + 1 row of x in flight.
    load_w(0, wbuf[0]);
    load_w(1, wbuf[1]);
    load_x(0, xbuf[0]);

    #pragma unroll
    for (int r = 0; r < RPW; ++r) {     // fully unrolled: static buffer indices
        const int b = b0 + r;

        // Issue next-row loads BEFORE consuming this row: the row-top wait
        // then only covers loads issued a full row ago.
        if (r + 1 < RPW) load_x(r + 1, xbuf[(r + 1) & 1]);
        if (r + 2 < RPW) load_w(r + 2, wbuf[(r + 2) % 3]);

        float4 (&w)[6] = wbuf[r % 3];
        float4 (&x)[6] = xbuf[r & 1];

        float acc = 0.0f;
        #pragma unroll
        for (int c = 0; c < 6; ++c)
            acc += w[c].x * x[c].x + w[c].y * x[c].y
                 + w[c].z * x[c].z + w[c].w * x[c].w;

        #pragma unroll
        for (int off = 32; off > 0; off >>= 1)
            acc += __shfl_xor(acc, off, 64);

        const float y = tanhf(acc + bk);
        if (lane == 0) out_hidden[b * Hn + k] = y;

        float* __restrict__ orow = out_wih + ((size_t)b * Hn + k) * Dn;
        #pragma unroll
        for (int c = 0; c < 6; ++c) {
            const int e = c * 64 + lane;
            const float4 a4 = sW[e];
            const float4 b4 = sW[384 + e];
            const float4 c4 = sW[768 + e];
            const float4 d4 = sW[1152 + e];
            nfloat4 o;
            o.x = w[c].x + ALPHA * (y * x[c].x * a4.x + x[c].x * b4.x + y * c4.x + d4.x);
            o.y = w[c].y + ALPHA * (y * x[c].y * a4.y + x[c].y * b4.y + y * c4.y + d4.y);
            o.z = w[c].z + ALPHA * (y * x[c].z * a4.z + x[c].z * b4.z + y * c4.z + d4.z);
            o.w = w[c].w + ALPHA * (y * x[c].w * a4.w + x[c].w * b4.w + y * c4.w + d4.w);
            __builtin_nontemporal_store(o, (nfloat4*)(orow + c * 256 + base));
        }
    }
}

extern "C" void kernel_launch(void* const* d_in, const int* in_sizes, int n_in,
                              void* d_out, int out_size, void* d_ws, size_t ws_size,
                              hipStream_t stream) {
    const float* inputs = (const float*)d_in[0];
    const float* hidden = (const float*)d_in[1];
    const float* wih    = (const float*)d_in[2];
    const float* Wa     = (const float*)d_in[3];
    const float* Wb     = (const float*)d_in[4];
    const float* Wc     = (const float*)d_in[5];
    const float* Wd     = (const float*)d_in[6];
    const float* bih    = (const float*)d_in[7];
    // d_in[8] = W_dop, d_in[9] = b_dop feed only _dopamine (not returned) -> skipped.

    float* out_hidden = (float*)d_out;                    // B*H floats
    float* out_wih    = (float*)d_out + (size_t)Bn * Hn;  // B*H*D floats

    prnn_fused_kernel<<<dim3(Hn), dim3(256), 0, stream>>>(
        inputs, hidden, wih, Wa, Wb, Wc, Wd, bih, out_hidden, out_wih);
}